// Round 2
// 275.108 us; speedup vs baseline: 1.0105x; 1.0105x over previous
//
#include <hip/hip_runtime.h>

#define N0 6400
#define NC 256
#define WW 80

using half8   = __attribute__((ext_vector_type(8))) _Float16;
using floatx4 = __attribute__((ext_vector_type(4))) float;
#define GLOBAL_AS __attribute__((address_space(1)))
#define LDS_AS    __attribute__((address_space(3)))

__device__ __forceinline__ unsigned long long packvi(float v, int i) {
    return ((unsigned long long)__float_as_uint(v) << 32) | (unsigned int)i;
}

// ---------------- K1: inverse L2 norms over channel dim ----------------
__global__ __launch_bounds__(256) void knorm(const float* __restrict__ f0,
                                             const float* __restrict__ f1,
                                             float* __restrict__ inv0,
                                             float* __restrict__ inv1) {
    int t = blockIdx.x * 256 + threadIdx.x;          // 0..12799
    const float* src = (t < N0) ? f0 : f1;
    int n = (t < N0) ? t : (t - N0);
    float s = 0.f;
#pragma unroll 8
    for (int c = 0; c < NC; ++c) {
        float v = src[c * N0 + n];
        s += v * v;
    }
    float inv = 1.0f / fmaxf(sqrtf(s), 1e-12f);
    if (t < N0) inv0[n] = inv; else inv1[n] = inv;
}

// -------- K2: transpose (C,N)->(N,256) fp16, normalized; z selects f0/f1
__global__ __launch_bounds__(256) void ktrans(const float* __restrict__ f0,
                                              const float* __restrict__ f1,
                                              const float* __restrict__ inv0,
                                              const float* __restrict__ inv1,
                                              _Float16* __restrict__ A2,
                                              _Float16* __restrict__ B2) {
    __shared__ float tile[32][33];
    const float* src = blockIdx.z ? f1 : f0;
    const float* inv = blockIdx.z ? inv1 : inv0;
    _Float16* dst    = blockIdx.z ? B2 : A2;
    int t = threadIdx.x;
    int n0 = blockIdx.x * 32, c0 = blockIdx.y * 32;
    int tx = t & 31, ty = t >> 5;                    // 32 x 8
#pragma unroll
    for (int u = 0; u < 4; ++u)
        tile[ty + u * 8][tx] = src[(c0 + ty + u * 8) * N0 + n0 + tx];
    __syncthreads();
    int row = t >> 3;            // 0..31 (local n)
    int cg  = (t & 7) * 4;       // 0..28 (local c, groups of 4)
    int n = n0 + row;
    float iv = inv[n];
    union { ushort4 u4; _Float16 h[4]; } pk;
#pragma unroll
    for (int u = 0; u < 4; ++u)
        pk.h[u] = (_Float16)(tile[cg + u][row] * iv);
    *(ushort4*)&dst[n * NC + c0 + cg] = pk.u4;
}

// ---------------- staging: full-K panels, XOR-swizzled on the fetch side
// LDS layout: [kk(4)][row(128)][64 halves], 64 KB per matrix. Within each
// 64-half k-quarter, the 16B chunk is placed at (chunk ^ (row&7)) — swizzle
// applied to the GLOBAL source so the LDS destination stays lane-linear
// (global_load_lds requirement).
__device__ __forceinline__ void stage_panel(const _Float16* __restrict__ G,
                                            unsigned short* lds, int r0, int tid) {
    int rl = tid >> 3;                               // 0..31
    int ch = ((tid & 7) ^ (rl & 7)) * 8;             // swizzled chunk (halves)
#pragma unroll
    for (int kk = 0; kk < 4; ++kk)
#pragma unroll
        for (int g = 0; g < 4; ++g) {
            const _Float16* ga = G + (r0 + g * 32 + rl) * NC + kk * 64 + ch;
            __builtin_amdgcn_global_load_lds((const GLOBAL_AS unsigned int*)ga,
                (LDS_AS unsigned int*)&lds[kk * 8192 + g * 2048 + tid * 8], 16, 0, 0);
        }
}

// ---------------- full-K (256) 128x128 tile MFMA: 128 MFMA/wave ---------
__device__ __forceinline__ void tile_mfma(const unsigned short* ldsA,
                                          const unsigned short* ldsB,
                                          int lane, int wm, int wn,
                                          floatx4 acc[4][4]) {
    int q = lane >> 4;
#pragma unroll
    for (int s = 0; s < 8; ++s) {
        int c  = s * 4 + q;                          // global k-chunk 0..31
        int kk = c >> 3, cq = c & 7;
        half8 af[4], bf[4];
#pragma unroll
        for (int mt = 0; mt < 4; ++mt) {
            int ra = wm * 64 + mt * 16 + (lane & 15);
            af[mt] = *(const half8*)&ldsA[kk * 8192 + ra * 64 + ((cq ^ (ra & 7)) * 8)];
            int rb = wn * 64 + mt * 16 + (lane & 15);
            bf[mt] = *(const half8*)&ldsB[kk * 8192 + rb * 64 + ((cq ^ (rb & 7)) * 8)];
        }
#pragma unroll
        for (int mt = 0; mt < 4; ++mt)
#pragma unroll
            for (int nt = 0; nt < 4; ++nt)
                acc[mt][nt] = __builtin_amdgcn_mfma_f32_16x16x32_f16(
                    af[mt], bf[nt], acc[mt][nt], 0, 0, 0);
    }
}

// ---------------- K3: GEMM pass 1 — row/col sums of exp(S) --------------
// Grid (50, 5): block = 128-row A panel x 1280-col B stripe (10 j-tiles).
// LDS = exactly 128 KiB; final reductions go straight to global atomics.
__global__ __launch_bounds__(256, 1) void kgemm1(const _Float16* __restrict__ A2,
                                                 const _Float16* __restrict__ B2,
                                                 float* __restrict__ rowsum,
                                                 float* __restrict__ colsum) {
    __shared__ __align__(16) unsigned short ldsA[32768], ldsB[32768];
    int tid = threadIdx.x, lane = tid & 63, wave = tid >> 6;
    int wm = wave & 1, wn = wave >> 1, q = lane >> 4;
    int i0 = blockIdx.x * 128, jp = blockIdx.y * 1280;

    stage_panel(A2, ldsA, i0, tid);                  // A panel staged ONCE
    float rsum[4][4] = {};                           // per-(mt,r) row partials

    for (int jt = 0; jt < 10; ++jt) {
        __syncthreads();                             // prev tile's reads done
        stage_panel(B2, ldsB, jp + jt * 128, tid);
        __syncthreads();                             // stage drained (vmcnt 0)
        floatx4 acc[4][4] = {};
        tile_mfma(ldsA, ldsB, lane, wm, wn, acc);

        float csum[4] = {0.f, 0.f, 0.f, 0.f};
#pragma unroll
        for (int mt = 0; mt < 4; ++mt)
#pragma unroll
            for (int r = 0; r < 4; ++r) {
                float rv = 0.f;
#pragma unroll
                for (int nt = 0; nt < 4; ++nt) {
                    float e = __expf(10.0f * acc[mt][nt][r]);
                    rv += e; csum[nt] += e;
                }
                rsum[mt][r] += rv;                   // rows fixed across tiles
            }
#pragma unroll
        for (int nt = 0; nt < 4; ++nt) {             // reduce cols across quads
            csum[nt] += __shfl_xor(csum[nt], 16);
            csum[nt] += __shfl_xor(csum[nt], 32);
        }
        if (lane < 16)
#pragma unroll
            for (int nt = 0; nt < 4; ++nt)
                atomicAdd(&colsum[jp + jt * 128 + wn * 64 + nt * 16 + lane], csum[nt]);
    }
    // one row reduction per block (not per tile), straight to global
#pragma unroll
    for (int mt = 0; mt < 4; ++mt)
#pragma unroll
        for (int r = 0; r < 4; ++r) {
            float v = rsum[mt][r];
            v += __shfl_xor(v, 1);
            v += __shfl_xor(v, 2);
            v += __shfl_xor(v, 4);
            v += __shfl_xor(v, 8);
            if ((lane & 15) == 0)
                atomicAdd(&rowsum[i0 + wm * 64 + mt * 16 + q * 4 + r], v);
        }
}

// ---------------- K4: GEMM pass 2 — P writes + fused argmax -------------
// rowsum/colsum hold SUMS (kinv folded in here as inline divides).
__global__ __launch_bounds__(256, 1) void kgemm2(const _Float16* __restrict__ A2,
                                                 const _Float16* __restrict__ B2,
                                                 const float* __restrict__ rowsum,
                                                 const float* __restrict__ colsum,
                                                 float* __restrict__ P,
                                                 unsigned long long* __restrict__ rowbest,
                                                 unsigned long long* __restrict__ colbest) {
    __shared__ __align__(16) unsigned short ldsA[32768], ldsB[32768];
    int tid = threadIdx.x, lane = tid & 63, wave = tid >> 6;
    int wm = wave & 1, wn = wave >> 1, q = lane >> 4;
    int i0 = blockIdx.x * 128, jp = blockIdx.y * 1280;

    stage_panel(A2, ldsA, i0, tid);

    float ir[4][4];                                  // row reciprocals, once
#pragma unroll
    for (int mt = 0; mt < 4; ++mt) {
        float4 v4 = *(const float4*)&rowsum[i0 + wm * 64 + mt * 16 + q * 4];
        ir[mt][0] = 1.0f / v4.x; ir[mt][1] = 1.0f / v4.y;
        ir[mt][2] = 1.0f / v4.z; ir[mt][3] = 1.0f / v4.w;
    }

    unsigned long long rbv[4][4] = {};               // row argmax across ALL tiles

    for (int jt = 0; jt < 10; ++jt) {
        __syncthreads();
        stage_panel(B2, ldsB, jp + jt * 128, tid);
        __syncthreads();
        floatx4 acc[4][4] = {};
        tile_mfma(ldsA, ldsB, lane, wm, wn, acc);

        int cb0 = jp + jt * 128 + wn * 64 + (lane & 15);
        float ic[4];
#pragma unroll
        for (int nt = 0; nt < 4; ++nt) ic[nt] = 1.0f / colsum[cb0 + nt * 16];

        unsigned long long colb[4] = {0ull, 0ull, 0ull, 0ull};
#pragma unroll
        for (int mt = 0; mt < 4; ++mt) {
            int rb0 = i0 + wm * 64 + mt * 16 + q * 4;
#pragma unroll
            for (int r = 0; r < 4; ++r) {
                int row = rb0 + r;
#pragma unroll
                for (int nt = 0; nt < 4; ++nt) {
                    float pv = __expf(20.0f * acc[mt][nt][r]) * ir[mt][r] * ic[nt];
                    P[row * N0 + cb0 + nt * 16] = pv;
                    unsigned long long pr = packvi(pv, cb0 + nt * 16);
                    if (pr > rbv[mt][r]) rbv[mt][r] = pr;
                    unsigned long long pc = packvi(pv, row);
                    if (pc > colb[nt]) colb[nt] = pc;
                }
            }
        }
#pragma unroll
        for (int nt = 0; nt < 4; ++nt) {             // per-tile col argmax
            unsigned long long o = __shfl_xor(colb[nt], 16);
            if (o > colb[nt]) colb[nt] = o;
            o = __shfl_xor(colb[nt], 32);
            if (o > colb[nt]) colb[nt] = o;
        }
        if (lane < 16)
#pragma unroll
            for (int nt = 0; nt < 4; ++nt)
                atomicMax(&colbest[cb0 + nt * 16], colb[nt]);
    }
    // one row-argmax reduction per block, straight to global
#pragma unroll
    for (int mt = 0; mt < 4; ++mt)
#pragma unroll
        for (int r = 0; r < 4; ++r) {
            unsigned long long v = rbv[mt][r];
#pragma unroll
            for (int s = 1; s < 16; s <<= 1) {
                unsigned long long o = __shfl_xor(v, s);
                if (o > v) v = o;
            }
            if ((lane & 15) == 0)
                atomicMax(&rowbest[i0 + wm * 64 + mt * 16 + q * 4 + r], v);
        }
}

// ---------------- K5: mutual-NN matching outputs -----------------------
__global__ __launch_bounds__(256) void kmatch(const unsigned long long* __restrict__ rowbest,
                                              const unsigned long long* __restrict__ colbest,
                                              float* __restrict__ out) {
    int i = blockIdx.x * 256 + threadIdx.x;      // 0..6399
    unsigned long long rb = rowbest[i];
    float conf = __uint_as_float((unsigned int)(rb >> 32));
    int jj = (int)(rb & 0xffffffffu);
    unsigned long long cb = colbest[jj];
    int i2 = (int)(cb & 0xffffffffu);
    bool valid = (i2 == i) && (conf > 0.2f);
    float vf = valid ? 1.0f : 0.0f;

    float* mk0   = out + 40960000;
    float* mk1   = out + 40972800;
    float* mconf = out + 40985600;
    float* vout  = out + 40992000;
    mk0[i * 2 + 0] = vf * (float)(i % WW);
    mk0[i * 2 + 1] = vf * (float)(i / WW);
    mk1[i * 2 + 0] = vf * (float)(jj % WW);
    mk1[i * 2 + 1] = vf * (float)(jj / WW);
    mconf[i] = valid ? conf : 0.0f;
    vout[i]  = vf;
}

extern "C" void kernel_launch(void* const* d_in, const int* in_sizes, int n_in,
                              void* d_out, int out_size, void* d_ws, size_t ws_size,
                              hipStream_t stream) {
    const float* f0 = (const float*)d_in[0];
    const float* f1 = (const float*)d_in[1];
    float* out = (float*)d_out;

    _Float16* A2 = (_Float16*)d_ws;                  // 6400x256 fp16
    _Float16* B2 = A2 + 6400 * 256;
    float* inv0   = (float*)(B2 + 6400 * 256);
    float* inv1   = inv0 + 6400;
    float* rowsum = inv1 + 6400;                     // then colsum (contiguous)
    float* colsum = rowsum + 6400;
    unsigned long long* rowbest = (unsigned long long*)(colsum + 6400);
    unsigned long long* colbest = rowbest + 6400;

    // zero rowsum/colsum (51,200 B) + rowbest/colbest (102,400 B), contiguous
    hipMemsetAsync(rowsum, 0, 153600, stream);

    knorm<<<50, 256, 0, stream>>>(f0, f1, inv0, inv1);
    ktrans<<<dim3(200, 8, 2), 256, 0, stream>>>(f0, f1, inv0, inv1, A2, B2);
    kgemm1<<<dim3(50, 5), 256, 0, stream>>>(A2, B2, rowsum, colsum);
    kgemm2<<<dim3(50, 5), 256, 0, stream>>>(A2, B2, rowsum, colsum,
                                            out, rowbest, colbest);
    kmatch<<<25, 256, 0, stream>>>(rowbest, colbest, out);
}

// Round 3
// 267.900 us; speedup vs baseline: 1.0377x; 1.0269x over previous
//
#include <hip/hip_runtime.h>

#define N0 6400
#define NC 256
#define WW 80

using half8   = __attribute__((ext_vector_type(8))) _Float16;
using floatx4 = __attribute__((ext_vector_type(4))) float;
#define GLOBAL_AS __attribute__((address_space(1)))
#define LDS_AS    __attribute__((address_space(3)))

__device__ __forceinline__ unsigned long long packvi(float v, int i) {
    return ((unsigned long long)__float_as_uint(v) << 32) | (unsigned int)i;
}

// ---------------- K1: inverse L2 norms + zero-init of reduction buffers
__global__ __launch_bounds__(256) void knorm(const float* __restrict__ f0,
                                             const float* __restrict__ f1,
                                             float* __restrict__ inv0,
                                             float* __restrict__ inv1,
                                             float* __restrict__ rowsum,
                                             float* __restrict__ colsum,
                                             unsigned long long* __restrict__ rowbest,
                                             unsigned long long* __restrict__ colbest) {
    int t = blockIdx.x * 256 + threadIdx.x;          // 0..12799
    if (t < N0) {                                    // replaces hipMemsetAsync
        rowsum[t] = 0.f; colsum[t] = 0.f;
        rowbest[t] = 0ull; colbest[t] = 0ull;
    }
    const float* src = (t < N0) ? f0 : f1;
    int n = (t < N0) ? t : (t - N0);
    float s = 0.f;
#pragma unroll 8
    for (int c = 0; c < NC; ++c) {
        float v = src[c * N0 + n];
        s += v * v;
    }
    float inv = 1.0f / fmaxf(sqrtf(s), 1e-12f);
    if (t < N0) inv0[n] = inv; else inv1[n] = inv;
}

// -------- K2: transpose (C,N)->(N,256) fp16, normalized; z selects f0/f1
__global__ __launch_bounds__(256) void ktrans(const float* __restrict__ f0,
                                              const float* __restrict__ f1,
                                              const float* __restrict__ inv0,
                                              const float* __restrict__ inv1,
                                              _Float16* __restrict__ A2,
                                              _Float16* __restrict__ B2) {
    __shared__ float tile[32][33];
    const float* src = blockIdx.z ? f1 : f0;
    const float* inv = blockIdx.z ? inv1 : inv0;
    _Float16* dst    = blockIdx.z ? B2 : A2;
    int t = threadIdx.x;
    int n0 = blockIdx.x * 32, c0 = blockIdx.y * 32;
    int tx = t & 31, ty = t >> 5;                    // 32 x 8
#pragma unroll
    for (int u = 0; u < 4; ++u)
        tile[ty + u * 8][tx] = src[(c0 + ty + u * 8) * N0 + n0 + tx];
    __syncthreads();
    int row = t >> 3;            // 0..31 (local n)
    int cg  = (t & 7) * 4;       // 0..28 (local c, groups of 4)
    int n = n0 + row;
    float iv = inv[n];
    union { ushort4 u4; _Float16 h[4]; } pk;
#pragma unroll
    for (int u = 0; u < 4; ++u)
        pk.h[u] = (_Float16)(tile[cg + u][row] * iv);
    *(ushort4*)&dst[n * NC + c0 + cg] = pk.u4;
}

// ---------------- staging: one 128-row full-K panel, XOR-swizzled fetch
// LDS layout: [kk(4)][row(128)][64 halves] = 32768 ushorts (64 KiB).
// 16B chunk placed at (chunk ^ (row&7)) — swizzle applied on the GLOBAL
// source so the LDS destination stays lane-linear (global_load_lds rule).
__device__ __forceinline__ void stage_panel(const _Float16* __restrict__ G,
                                            unsigned short* lds, int r0, int tid) {
    int rl = tid >> 3;                               // 0..31
    int ch = ((tid & 7) ^ (rl & 7)) * 8;             // swizzled chunk (halves)
#pragma unroll
    for (int kk = 0; kk < 4; ++kk)
#pragma unroll
        for (int g = 0; g < 4; ++g) {
            const _Float16* ga = G + (r0 + g * 32 + rl) * NC + kk * 64 + ch;
            __builtin_amdgcn_global_load_lds((const GLOBAL_AS unsigned int*)ga,
                (LDS_AS unsigned int*)&lds[kk * 8192 + g * 2048 + tid * 8], 16, 0, 0);
        }
}

// ---------------- K3: GEMM pass 1 — row/col sums of exp(S) --------------
// Grid (50,5): block = 128-row A panel x 1280-col B stripe (10 j-tiles).
// A fragments hoisted to registers (af[4][8] = 128 VGPR); A's LDS space is
// then reused as the second B buffer -> double-buffered, stage-ahead B.
__global__ __launch_bounds__(256, 1) void kgemm1(const _Float16* __restrict__ A2,
                                                 const _Float16* __restrict__ B2,
                                                 float* __restrict__ rowsum,
                                                 float* __restrict__ colsum) {
    __shared__ __align__(16) unsigned short lds[65536];   // 128 KiB
    int tid = threadIdx.x, lane = tid & 63, wave = tid >> 6;
    int wm = wave & 1, wn = wave >> 1, q = lane >> 4;
    int i0 = blockIdx.x * 128, jp = blockIdx.y * 1280;

    stage_panel(A2, lds, i0, tid);                   // A panel -> [0:32768)
    stage_panel(B2, lds + 32768, jp, tid);           // B tile 0 -> [32768:65536)
    __syncthreads();                                 // both staged (vmcnt 0)

    half8 af[4][8];                                  // A fragments, whole K
#pragma unroll
    for (int mt = 0; mt < 4; ++mt)
#pragma unroll
        for (int s = 0; s < 8; ++s) {
            int c = s * 4 + q, kk = c >> 3, cq = c & 7;
            int ra = wm * 64 + mt * 16 + (lane & 15);
            af[mt][s] = *(const half8*)&lds[kk * 8192 + ra * 64 + ((cq ^ (ra & 7)) * 8)];
        }
    __syncthreads();                                 // A reads done; area reusable

    float rsum[4][4] = {};                           // per-(mt,r) row partials

    for (int jt = 0; jt < 10; ++jt) {
        const unsigned short* cur = lds + ((jt & 1) ? 0 : 32768);
        if (jt < 9)                                  // stage-ahead into other buf
            stage_panel(B2, lds + ((jt & 1) ? 32768 : 0), jp + (jt + 1) * 128, tid);

        floatx4 acc[4][4] = {};
#pragma unroll
        for (int s = 0; s < 8; ++s) {
            int c = s * 4 + q, kk = c >> 3, cq = c & 7;
            half8 bf[4];
#pragma unroll
            for (int nt = 0; nt < 4; ++nt) {
                int rb = wn * 64 + nt * 16 + (lane & 15);
                bf[nt] = *(const half8*)&cur[kk * 8192 + rb * 64 + ((cq ^ (rb & 7)) * 8)];
            }
#pragma unroll
            for (int mt = 0; mt < 4; ++mt)
#pragma unroll
                for (int nt = 0; nt < 4; ++nt)
                    acc[mt][nt] = __builtin_amdgcn_mfma_f32_16x16x32_f16(
                        af[mt][s], bf[nt], acc[mt][nt], 0, 0, 0);
        }

        float csum[4] = {0.f, 0.f, 0.f, 0.f};
#pragma unroll
        for (int mt = 0; mt < 4; ++mt)
#pragma unroll
            for (int r = 0; r < 4; ++r) {
                float rv = 0.f;
#pragma unroll
                for (int nt = 0; nt < 4; ++nt) {
                    float e = __expf(10.0f * acc[mt][nt][r]);
                    rv += e; csum[nt] += e;
                }
                rsum[mt][r] += rv;                   // rows fixed across tiles
            }
#pragma unroll
        for (int nt = 0; nt < 4; ++nt) {             // reduce cols across quads
            csum[nt] += __shfl_xor(csum[nt], 16);
            csum[nt] += __shfl_xor(csum[nt], 32);
        }
        if (lane < 16)
#pragma unroll
            for (int nt = 0; nt < 4; ++nt)
                atomicAdd(&colsum[jp + jt * 128 + wn * 64 + nt * 16 + lane], csum[nt]);
        __syncthreads();                             // stage drained + reads done
    }
    // one row reduction per block, straight to global
#pragma unroll
    for (int mt = 0; mt < 4; ++mt)
#pragma unroll
        for (int r = 0; r < 4; ++r) {
            float v = rsum[mt][r];
            v += __shfl_xor(v, 1);
            v += __shfl_xor(v, 2);
            v += __shfl_xor(v, 4);
            v += __shfl_xor(v, 8);
            if ((lane & 15) == 0)
                atomicAdd(&rowsum[i0 + wm * 64 + mt * 16 + q * 4 + r], v);
        }
}

// ---------------- K4: GEMM pass 2 — P writes + fused argmax -------------
// rowsum/colsum hold SUMS (reciprocals inlined here). Same pipeline as K3.
__global__ __launch_bounds__(256, 1) void kgemm2(const _Float16* __restrict__ A2,
                                                 const _Float16* __restrict__ B2,
                                                 const float* __restrict__ rowsum,
                                                 const float* __restrict__ colsum,
                                                 float* __restrict__ P,
                                                 unsigned long long* __restrict__ rowbest,
                                                 unsigned long long* __restrict__ colbest) {
    __shared__ __align__(16) unsigned short lds[65536];   // 128 KiB
    int tid = threadIdx.x, lane = tid & 63, wave = tid >> 6;
    int wm = wave & 1, wn = wave >> 1, q = lane >> 4;
    int i0 = blockIdx.x * 128, jp = blockIdx.y * 1280;

    stage_panel(A2, lds, i0, tid);
    stage_panel(B2, lds + 32768, jp, tid);
    __syncthreads();

    half8 af[4][8];
#pragma unroll
    for (int mt = 0; mt < 4; ++mt)
#pragma unroll
        for (int s = 0; s < 8; ++s) {
            int c = s * 4 + q, kk = c >> 3, cq = c & 7;
            int ra = wm * 64 + mt * 16 + (lane & 15);
            af[mt][s] = *(const half8*)&lds[kk * 8192 + ra * 64 + ((cq ^ (ra & 7)) * 8)];
        }
    __syncthreads();

    float ir[4][4];                                  // row reciprocals, once
#pragma unroll
    for (int mt = 0; mt < 4; ++mt) {
        float4 v4 = *(const float4*)&rowsum[i0 + wm * 64 + mt * 16 + q * 4];
        ir[mt][0] = 1.0f / v4.x; ir[mt][1] = 1.0f / v4.y;
        ir[mt][2] = 1.0f / v4.z; ir[mt][3] = 1.0f / v4.w;
    }

    unsigned long long rbv[4][4] = {};               // row argmax across ALL tiles

    for (int jt = 0; jt < 10; ++jt) {
        const unsigned short* cur = lds + ((jt & 1) ? 0 : 32768);
        if (jt < 9)
            stage_panel(B2, lds + ((jt & 1) ? 32768 : 0), jp + (jt + 1) * 128, tid);

        floatx4 acc[4][4] = {};
#pragma unroll
        for (int s = 0; s < 8; ++s) {
            int c = s * 4 + q, kk = c >> 3, cq = c & 7;
            half8 bf[4];
#pragma unroll
            for (int nt = 0; nt < 4; ++nt) {
                int rb = wn * 64 + nt * 16 + (lane & 15);
                bf[nt] = *(const half8*)&cur[kk * 8192 + rb * 64 + ((cq ^ (rb & 7)) * 8)];
            }
#pragma unroll
            for (int mt = 0; mt < 4; ++mt)
#pragma unroll
                for (int nt = 0; nt < 4; ++nt)
                    acc[mt][nt] = __builtin_amdgcn_mfma_f32_16x16x32_f16(
                        af[mt][s], bf[nt], acc[mt][nt], 0, 0, 0);
        }

        int cb0 = jp + jt * 128 + wn * 64 + (lane & 15);
        float ic[4];
#pragma unroll
        for (int nt = 0; nt < 4; ++nt) ic[nt] = 1.0f / colsum[cb0 + nt * 16];

        unsigned long long colb[4] = {0ull, 0ull, 0ull, 0ull};
#pragma unroll
        for (int mt = 0; mt < 4; ++mt) {
            int rb0 = i0 + wm * 64 + mt * 16 + q * 4;
#pragma unroll
            for (int r = 0; r < 4; ++r) {
                int row = rb0 + r;
#pragma unroll
                for (int nt = 0; nt < 4; ++nt) {
                    float pv = __expf(20.0f * acc[mt][nt][r]) * ir[mt][r] * ic[nt];
                    P[row * N0 + cb0 + nt * 16] = pv;
                    unsigned long long pr = packvi(pv, cb0 + nt * 16);
                    if (pr > rbv[mt][r]) rbv[mt][r] = pr;
                    unsigned long long pc = packvi(pv, row);
                    if (pc > colb[nt]) colb[nt] = pc;
                }
            }
        }
#pragma unroll
        for (int nt = 0; nt < 4; ++nt) {             // per-tile col argmax
            unsigned long long o = __shfl_xor(colb[nt], 16);
            if (o > colb[nt]) colb[nt] = o;
            o = __shfl_xor(colb[nt], 32);
            if (o > colb[nt]) colb[nt] = o;
        }
        if (lane < 16)
#pragma unroll
            for (int nt = 0; nt < 4; ++nt)
                atomicMax(&colbest[cb0 + nt * 16], colb[nt]);
        __syncthreads();
    }
    // one row-argmax reduction per block, straight to global
#pragma unroll
    for (int mt = 0; mt < 4; ++mt)
#pragma unroll
        for (int r = 0; r < 4; ++r) {
            unsigned long long v = rbv[mt][r];
#pragma unroll
            for (int s = 1; s < 16; s <<= 1) {
                unsigned long long o = __shfl_xor(v, s);
                if (o > v) v = o;
            }
            if ((lane & 15) == 0)
                atomicMax(&rowbest[i0 + wm * 64 + mt * 16 + q * 4 + r], v);
        }
}

// ---------------- K5: mutual-NN matching outputs -----------------------
__global__ __launch_bounds__(256) void kmatch(const unsigned long long* __restrict__ rowbest,
                                              const unsigned long long* __restrict__ colbest,
                                              float* __restrict__ out) {
    int i = blockIdx.x * 256 + threadIdx.x;      // 0..6399
    unsigned long long rb = rowbest[i];
    float conf = __uint_as_float((unsigned int)(rb >> 32));
    int jj = (int)(rb & 0xffffffffu);
    unsigned long long cb = colbest[jj];
    int i2 = (int)(cb & 0xffffffffu);
    bool valid = (i2 == i) && (conf > 0.2f);
    float vf = valid ? 1.0f : 0.0f;

    float* mk0   = out + 40960000;
    float* mk1   = out + 40972800;
    float* mconf = out + 40985600;
    float* vout  = out + 40992000;
    mk0[i * 2 + 0] = vf * (float)(i % WW);
    mk0[i * 2 + 1] = vf * (float)(i / WW);
    mk1[i * 2 + 0] = vf * (float)(jj % WW);
    mk1[i * 2 + 1] = vf * (float)(jj / WW);
    mconf[i] = valid ? conf : 0.0f;
    vout[i]  = vf;
}

extern "C" void kernel_launch(void* const* d_in, const int* in_sizes, int n_in,
                              void* d_out, int out_size, void* d_ws, size_t ws_size,
                              hipStream_t stream) {
    const float* f0 = (const float*)d_in[0];
    const float* f1 = (const float*)d_in[1];
    float* out = (float*)d_out;

    _Float16* A2 = (_Float16*)d_ws;                  // 6400x256 fp16
    _Float16* B2 = A2 + 6400 * 256;
    float* inv0   = (float*)(B2 + 6400 * 256);
    float* inv1   = inv0 + 6400;
    float* rowsum = inv1 + 6400;                     // then colsum (contiguous)
    float* colsum = rowsum + 6400;
    unsigned long long* rowbest = (unsigned long long*)(colsum + 6400);
    unsigned long long* colbest = rowbest + 6400;

    knorm<<<50, 256, 0, stream>>>(f0, f1, inv0, inv1,
                                  rowsum, colsum, rowbest, colbest);
    ktrans<<<dim3(200, 8, 2), 256, 0, stream>>>(f0, f1, inv0, inv1, A2, B2);
    kgemm1<<<dim3(50, 5), 256, 0, stream>>>(A2, B2, rowsum, colsum);
    kgemm2<<<dim3(50, 5), 256, 0, stream>>>(A2, B2, rowsum, colsum,
                                            out, rowbest, colbest);
    kmatch<<<25, 256, 0, stream>>>(rowbest, colbest, out);
}